// Round 8
// baseline (150.780 us; speedup 1.0000x reference)
//
#include <hip/hip_runtime.h>
#include <math.h>

// ---------------------------------------------------------------------------
// Barrier_Net, full-f16 MFMA (16x16x32), TWO-GROUPS-PER-WAVE pipeline (R19).
// (Resubmission of R19 — previous round failed in the harness with
//  "MI355X container failed twice" before any compile/run of this code.)
// Each wave handles 2 independent 16-row groups END-TO-END with stage bodies
// duplicated over {g0,g1} in the same scope -> the compiler's static
// scheduler interleaves the two dependency chains (ILP where R14 showed TLP
// can't help: all-wave same-pattern stalls). B-fragment loads from wsf are
// shared by both groups (halves the per-group ~200cyc L2-latency B loads
// that sit at every stage entry).
// vs R18 (138.1 us, bn_main ~34.7): S1N/S1O accS reverted to R16 C-chained
// form (saves the Bspo/Apo register blocks to fit 2x acc under the 128-VGPR
// cap; extra MFMAs land on the idle matrix pipe - R18 proved MFMA count
// irrelevant). No __syncthreads; wave-private LDS with lds_order() fences
// (R11-proven). R17 algebraic fusion kept (FN/FO=0.5*Wp2@Wr1, ZN/ZO, WG with
// combined bias row). R16 relu identity kept.
// A-frag: A[m=lane&15][k=(lane>>4)*8+j]; B-frag: B[k=(lane>>4)*8+j][n=lane&15]
// C/D: col=lane&15, row=(lane>>4)*4+reg.  (HW-verified R7..R12)
// LDS: 8 groups x 4864 B = 38912 B/block -> 4 blk/CU = 16 waves/CU.
// __launch_bounds__(256,4) -> VGPR cap 128 (peak live ~100).
// nb = 131072 -> 8192 groups -> 4096 waves -> 1024 blocks, no partials.
// ---------------------------------------------------------------------------

typedef __attribute__((ext_vector_type(8))) _Float16 f16x8;
typedef __attribute__((ext_vector_type(2))) __fp16 fp16x2;
typedef __attribute__((ext_vector_type(4))) float f32x4;

#define XW 85     // floats per input row

// ---- B-frag table in d_ws (R18 layout kept; SPN/SPO unused by main) ----
#define FR_S1N  0    // 4: Wp1n K=4, bias bp1n @k4
#define FR_S1O  4    // 4: Wp1o K=2, bias bp1o @k2
#define FR_FN   8    // 8: 0.5*Wp2n@Wr1n  (kk*4+nt)
#define FR_FO   16   // 8: 0.5*Wp2o@Wr1o
#define FR_ZN   24   // 8: Wr2n@Wpsi1[0:16]
#define FR_ZO   32   // 8: Wr2o@Wpsi1[16:32]
#define FR_WG   40   // 4: Wpsi1[32:36] K=4, combined PSI1 bias @k4
#define FR_PSI2 44   // 2: Wpsi2 K=64 N=2
#define FR_SPN  46   // 4: (unused in R19 main)
#define FR_SPO  50   // 4: (unused in R19 main)
#define N_FRAGS 54
// f32 bias area at 54*512 f16: [0..63]=bias_fn, [64..127]=bias_fo,
//                              [128..191]=16*bp1n, [192..255]=8*bp1o

// ---- per-GROUP LDS layout (bytes); 8 groups (2/wave x 4 waves) per block ----
#define BIG_STR 144
#define L_BIG  0        // 2304  NBA staging / h1n / z_n / h3
#define L_BIG2 2304     // 2304  h1o / z_o
#define L_OUT  4608     // 128
#define L_BAR  4736     // 128
#define GRP_LDS 4864    // x8 groups = 38912 B/block
#define NBA_STR 136     // staging tile stride inside BIG region

#define H16_ONE 0x00003C00u   // f16 1.0 in low half of a dword

__device__ __forceinline__ float fast_rcp(float x)  { return __builtin_amdgcn_rcpf(x); }
__device__ __forceinline__ float fast_sqrt(float x) { return __builtin_amdgcn_sqrtf(x); }

__device__ __forceinline__ float two_tanh(float a) {
    float ax = fabsf(a);
    float e = __expf(2.0f * ax);
    float t = 1.0f - 2.0f * fast_rcp(e + 1.0f);
    return copysignf(2.0f * t, a);
}

// Compiler-only ordering barrier for wave-private LDS (R11-proven safe).
__device__ __forceinline__ void lds_order() {
    __asm__ __volatile__("" ::: "memory");
}

__device__ __forceinline__ unsigned pk2(float a, float b) {
    union { fp16x2 h; unsigned u; } t;
    t.h = __builtin_amdgcn_cvt_pkrtz(a, b);
    return t.u;
}
__device__ __forceinline__ f16x8 lds_af(const char* area, int stride, int off, int lane) {
    int mm = lane & 15, qq = lane >> 4;
    return *(const f16x8*)(area + mm * stride + off + qq * 16);
}
__device__ __forceinline__ f16x8 load_bh(const _Float16* wsf, int frag, int lane) {
    return ((const f16x8*)(wsf + (size_t)frag * 512))[lane];
}
__device__ __forceinline__ f32x4 cinit(float b) {
    f32x4 c; c[0] = b; c[1] = b; c[2] = b; c[3] = b; return c;
}
__device__ __forceinline__ f32x4 mfma1(f16x8 a, f16x8 b, f32x4 c) {
    return __builtin_amdgcn_mfma_f32_16x16x32_f16(a, b, c, 0, 0, 0);
}

// ---------------------------------------------------------------------------
// prep: pack (pre-composed) weights into f16 B-frag blocks + f32 bias rows.
// (unchanged from R18)
// ---------------------------------------------------------------------------
__global__ void bn_prep(const float* __restrict__ Wp1n, const float* __restrict__ Wp2n,
                        const float* __restrict__ Wr1n, const float* __restrict__ Wr2n,
                        const float* __restrict__ Wp1o, const float* __restrict__ Wp2o,
                        const float* __restrict__ Wr1o, const float* __restrict__ Wr2o,
                        const float* __restrict__ Wpsi1, const float* __restrict__ Wpsi2,
                        const float* __restrict__ bp1n, const float* __restrict__ bp1o,
                        const float* __restrict__ bp2n, const float* __restrict__ bp2o,
                        const float* __restrict__ br1n, const float* __restrict__ br1o,
                        const float* __restrict__ br2n, const float* __restrict__ br2o,
                        const float* __restrict__ bpsi1,
                        _Float16* __restrict__ wsf)
{
    int f = blockIdx.x;
    int lane = threadIdx.x;   // 64
    int q = lane >> 4, c = lane & 15;

    if (f >= N_FRAGS) {
        float* dst = (float*)(wsf + (size_t)N_FRAGS * 512) + (f - N_FRAGS) * 64;
        if (lane < 64) {
            if (f == N_FRAGS) {
                float s = 0.f;
                for (int e = 0; e < 16; ++e) s = fmaf(bp2n[e], Wr1n[e * 64 + lane], s);
                dst[lane] = 16.f * s + br1n[lane];
            } else if (f == N_FRAGS + 1) {
                float s = 0.f;
                for (int e = 0; e < 16; ++e) s = fmaf(bp2o[e], Wr1o[e * 64 + lane], s);
                dst[lane] = 8.f * s + br1o[lane];
            } else if (f == N_FRAGS + 2) {
                dst[lane] = 16.f * bp1n[lane];
            } else {
                dst[lane] = 8.f * bp1o[lane];
            }
        }
        return;
    }

    _Float16* dstf = wsf + (size_t)f * 512 + lane * 8;

    if (f < 8) {
        const float* W   = (f < 4) ? Wp1n : Wp1o;
        const float* bia = (f < 4) ? bp1n : bp1o;
        int K  = (f < 4) ? 4 : 2;
        int nt = f & 3;
        for (int j = 0; j < 8; ++j) {
            int k = q * 8 + j;
            int n = nt * 16 + c;
            float v = 0.f;
            if (k < K) v = W[k * 64 + n];
            else if (k == K) v = bia[n];
            dstf[j] = (_Float16)v;
        }
    } else if (f < 24) {
        int rel = (f - 8) & 7;
        bool isN = f < 16;
        const float* Wa = isN ? Wp2n : Wp2o;
        const float* Wb = isN ? Wr1n : Wr1o;
        int kk = rel >> 2, nt = rel & 3;
        for (int j = 0; j < 8; ++j) {
            int k = kk * 32 + q * 8 + j;
            int n = nt * 16 + c;
            float s = 0.f;
            for (int e = 0; e < 16; ++e) s = fmaf(Wa[k * 16 + e], Wb[e * 64 + n], s);
            dstf[j] = (_Float16)(0.5f * s);
        }
    } else if (f < 40) {
        int rel = (f - 24) & 7;
        bool isN = f < 32;
        const float* Wa = isN ? Wr2n : Wr2o;
        int roff = isN ? 0 : 16;
        int kk = rel >> 2, nt = rel & 3;
        for (int j = 0; j < 8; ++j) {
            int k = kk * 32 + q * 8 + j;
            int n = nt * 16 + c;
            float s = 0.f;
            for (int e = 0; e < 16; ++e) s = fmaf(Wa[k * 16 + e], Wpsi1[(roff + e) * 64 + n], s);
            dstf[j] = (_Float16)s;
        }
    } else if (f < 44) {
        int nt = f - 40;
        for (int j = 0; j < 8; ++j) {
            int k = q * 8 + j;
            int n = nt * 16 + c;
            float v = 0.f;
            if (k < 4) v = Wpsi1[(32 + k) * 64 + n];
            else if (k == 4) {
                float s = bpsi1[n];
                for (int e = 0; e < 16; ++e) {
                    s = fmaf(br2n[e], Wpsi1[e * 64 + n], s);
                    s = fmaf(br2o[e], Wpsi1[(16 + e) * 64 + n], s);
                }
                v = s;
            }
            dstf[j] = (_Float16)v;
        }
    } else if (f < 46) {
        int kk = f - 44;
        for (int j = 0; j < 8; ++j) {
            int k = kk * 32 + q * 8 + j;
            float v = (c < 2) ? Wpsi2[k * 2 + c] : 0.f;
            dstf[j] = (_Float16)v;
        }
    } else if (f < 50) {
        int nt = f - 46;
        for (int j = 0; j < 8; ++j) {
            int k = q * 8 + j;
            int n = nt * 16 + c;
            dstf[j] = (_Float16)Wp1n[(k & 3) * 64 + n];
        }
    } else {
        int nt = f - 50;
        for (int j = 0; j < 8; ++j) {
            int k = q * 8 + j;
            int n = nt * 16 + c;
            float v = (k < 16) ? Wp1o[(k & 1) * 64 + n] : 0.f;
            dstf[j] = (_Float16)v;
        }
    }
}

// ---------------------------------------------------------------------------
// main: 2 groups per wave; block 256 = 4 waves = 8 groups.
// ---------------------------------------------------------------------------
__global__ __launch_bounds__(256, 4) void bn_main(
    const float* __restrict__ x, const _Float16* __restrict__ wsf,
    const float* __restrict__ bpsi2,
    float* __restrict__ out, int nb)
{
    __shared__ char smem[8 * GRP_LDS];
    const int lane = threadIdx.x & 63;
    const int wid  = threadIdx.x >> 6;            // 0..3
    const int g0   = blockIdx.x * 8 + wid * 2;    // first group of this wave
    const int row0 = g0 * 16;
    const int row1 = row0 + 16;

    char* Gl0  = smem + (wid * 2) * GRP_LDS;
    char* Gl1  = Gl0 + GRP_LDS;
    char* BIG0 = Gl0 + L_BIG;   char* BIG1 = Gl1 + L_BIG;
    char* BG20 = Gl0 + L_BIG2;  char* BG21 = Gl1 + L_BIG2;
    char* OUT0 = Gl0 + L_OUT;   char* OUT1 = Gl1 + L_OUT;
    char* BAR0 = Gl0 + L_BAR;   char* BAR1 = Gl1 + L_BAR;
    char* NBA0 = BIG0;          char* NBA1 = BIG1;   // staging aliases BIG

    const int m = lane & 15, q = lane >> 4, c = m;
    const float* xg0   = x + (size_t)row0 * XW;
    const float* xg1   = x + (size_t)row1 * XW;
    const float* xrow0 = xg0 + (size_t)m * XW;
    const float* xrow1 = xg1 + (size_t)m * XW;

    const float* BFN = (const float*)(wsf + (size_t)N_FRAGS * 512);  // bias_fn
    const float* BFO = BFN + 64;                                     // bias_fo

    const f32x4 ZC = cinit(0.f);

    // ---- stage neighbor features -> NBA0/NBA1 (interleaved loads) ----
    {
        int ln5 = lane >> 5;                 // 0/1
        int pr  = lane & 31;
        int mm0 = pr >> 1, fp = pr & 1;
        int dbo = mm0 * NBA_STR + fp * 4;
        const float* s00 = xg0 + (size_t)ln5 * XW + 5 + pr * 2;
        const float* s10 = xg1 + (size_t)ln5 * XW + 5 + pr * 2;
        #pragma unroll
        for (int t = 0; t < 8; ++t) {
            const float* sa = s00 + (size_t)(2 * t) * XW;
            const float* sb = s10 + (size_t)(2 * t) * XW;
            *(unsigned*)(NBA0 + dbo + (2 * t + ln5) * 8) = pk2(sa[0], sa[1]);
            *(unsigned*)(NBA1 + dbo + (2 * t + ln5) * 8) = pk2(sb[0], sb[1]);
        }
    }

    // ---- gA (PSI A-operand) built early, 8 VGPR held ----
    union { f16x8 v; unsigned u[4]; } gA0, gA1;
    gA0.u[0] = pk2(xrow0[1], xrow0[2]);
    gA0.u[1] = pk2(xrow0[3], xrow0[4]);
    gA0.u[2] = H16_ONE; gA0.u[3] = 0;
    gA1.u[0] = pk2(xrow1[1], xrow1[2]);
    gA1.u[1] = pk2(xrow1[3], xrow1[4]);
    gA1.u[2] = H16_ONE; gA1.u[3] = 0;

    // ---- obstacle features -> registers ----
    unsigned obs0[8], obs1[8];
    #pragma unroll
    for (int t = 0; t < 8; ++t) {
        obs0[t] = pk2(xrow0[69 + 2 * t], xrow0[70 + 2 * t]);
        obs1[t] = pk2(xrow1[69 + 2 * t], xrow1[70 + 2 * t]);
    }

    // ---- barrier terms for both rows ----
    {
        float bx0 = 0.f, by0 = 0.f, bx1 = 0.f, by1 = 0.f;
        #pragma unroll
        for (int i = 0; i < 4; ++i) {
            int n = 4 * q + i;
            float p0x = -xrow0[5 + 4 * n], p0y = -xrow0[6 + 4 * n];
            float n0 = fast_sqrt(p0x * p0x + p0y * p0y);
            float c0 = 0.05f * fast_rcp(n0 * (n0 - 0.3f));
            bx0 = fmaf(c0, p0x, bx0); by0 = fmaf(c0, p0y, by0);
            float p1x = -xrow1[5 + 4 * n], p1y = -xrow1[6 + 4 * n];
            float n1 = fast_sqrt(p1x * p1x + p1y * p1y);
            float c1 = 0.05f * fast_rcp(n1 * (n1 - 0.3f));
            bx1 = fmaf(c1, p1x, bx1); by1 = fmaf(c1, p1y, by1);
        }
        #pragma unroll
        for (int i = 0; i < 2; ++i) {
            int o = 2 * q + i;
            float p0x = -xrow0[69 + 2 * o], p0y = -xrow0[70 + 2 * o];
            float n0 = fast_sqrt(p0x * p0x + p0y * p0y);
            float c0 = 0.05f * fast_rcp(n0 * (n0 - 0.3f));
            bx0 = fmaf(c0, p0x, bx0); by0 = fmaf(c0, p0y, by0);
            float p1x = -xrow1[69 + 2 * o], p1y = -xrow1[70 + 2 * o];
            float n1 = fast_sqrt(p1x * p1x + p1y * p1y);
            float c1 = 0.05f * fast_rcp(n1 * (n1 - 0.3f));
            bx1 = fmaf(c1, p1x, bx1); by1 = fmaf(c1, p1y, by1);
        }
        bx0 += __shfl_xor(bx0, 16); by0 += __shfl_xor(by0, 16);
        bx0 += __shfl_xor(bx0, 32); by0 += __shfl_xor(by0, 32);
        bx1 += __shfl_xor(bx1, 16); by1 += __shfl_xor(by1, 16);
        bx1 += __shfl_xor(bx1, 32); by1 += __shfl_xor(by1, 32);
        if (q == 0) {
            float2 b0; b0.x = bx0; b0.y = by0; *(float2*)(BAR0 + m * 8) = b0;
            float2 b1; b1.x = bx1; b1.y = by1; *(float2*)(BAR1 + m * 8) = b1;
        }
    }

    // ========== S1O both groups (register-only; NBA stores still landing) ==
    // Sum relu(x) = (Sum x + Sum|x|)/2; accS C-chained; bias row k=2 (A 1.0).
    {
        f16x8 Bs1o[4];
        #pragma unroll
        for (int nt = 0; nt < 4; ++nt) Bs1o[nt] = load_bh(wsf, FR_S1O + nt, lane);

        f32x4 aS0[4], aA0[4], aS1[4], aA1[4];
        #pragma unroll
        for (int nt = 0; nt < 4; ++nt) {
            aS0[nt] = cinit(0.f); aA0[nt] = cinit(0.f);
            aS1[nt] = cinit(0.f); aA1[nt] = cinit(0.f);
        }
        union { f16x8 v; unsigned u[4]; } A0, A1;
        A0.u[1] = H16_ONE; A0.u[2] = 0; A0.u[3] = 0;
        A1.u[1] = H16_ONE; A1.u[2] = 0; A1.u[3] = 0;
        #pragma unroll
        for (int oo = 0; oo < 8; ++oo) {
            A0.u[0] = obs0[oo];
            A1.u[0] = obs1[oo];
            #pragma unroll
            for (int nt = 0; nt < 4; ++nt) {
                aS0[nt] = mfma1(A0.v, Bs1o[nt], aS0[nt]);
                f32x4 c0 = mfma1(A0.v, Bs1o[nt], ZC);
                aS1[nt] = mfma1(A1.v, Bs1o[nt], aS1[nt]);
                f32x4 c1 = mfma1(A1.v, Bs1o[nt], ZC);
                #pragma unroll
                for (int reg = 0; reg < 4; ++reg) {
                    aA0[nt][reg] += fabsf(c0[reg]);
                    aA1[nt][reg] += fabsf(c1[reg]);
                }
            }
        }
        #pragma unroll
        for (int nt = 0; nt < 4; ++nt)
            #pragma unroll
            for (int reg = 0; reg < 4; ++reg) {
                *(_Float16*)(BG20 + (q * 4 + reg) * BIG_STR + (nt * 16 + c) * 2)
                    = (_Float16)(aS0[nt][reg] + aA0[nt][reg]);
                *(_Float16*)(BG21 + (q * 4 + reg) * BIG_STR + (nt * 16 + c) * 2)
                    = (_Float16)(aS1[nt][reg] + aA1[nt][reg]);
            }
    }
    lds_order();   // NBA staging stores ordered before S1N reads

    // ========== S1N both groups (interleaved chains, shared B) =============
    {
        f16x8 Bs1n[4];
        #pragma unroll
        for (int nt = 0; nt < 4; ++nt) Bs1n[nt] = load_bh(wsf, FR_S1N + nt, lane);

        const int m8 = m * 8;
        f32x4 aS0[4], aA0[4], aS1[4], aA1[4];
        #pragma unroll
        for (int nt = 0; nt < 4; ++nt) {
            aS0[nt] = cinit(0.f); aA0[nt] = cinit(0.f);
            aS1[nt] = cinit(0.f); aA1[nt] = cinit(0.f);
        }
        union { f16x8 v; unsigned u[4]; uint2 h[2]; } A0, A1;
        A0.u[2] = H16_ONE; A0.u[3] = 0;
        A1.u[2] = H16_ONE; A1.u[3] = 0;
        #pragma unroll
        for (int mm = 0; mm < 16; ++mm) {
            A0.h[0] = *(const uint2*)(NBA0 + mm * NBA_STR + m8);
            A1.h[0] = *(const uint2*)(NBA1 + mm * NBA_STR + m8);
            #pragma unroll
            for (int nt = 0; nt < 4; ++nt) {
                aS0[nt] = mfma1(A0.v, Bs1n[nt], aS0[nt]);
                f32x4 c0 = mfma1(A0.v, Bs1n[nt], ZC);
                aS1[nt] = mfma1(A1.v, Bs1n[nt], aS1[nt]);
                f32x4 c1 = mfma1(A1.v, Bs1n[nt], ZC);
                #pragma unroll
                for (int reg = 0; reg < 4; ++reg) {
                    aA0[nt][reg] += fabsf(c0[reg]);
                    aA1[nt][reg] += fabsf(c1[reg]);
                }
            }
        }
        lds_order();   // NBA reads done; BIG stores below alias it
        #pragma unroll
        for (int nt = 0; nt < 4; ++nt)
            #pragma unroll
            for (int reg = 0; reg < 4; ++reg) {
                *(_Float16*)(BIG0 + (q * 4 + reg) * BIG_STR + (nt * 16 + c) * 2)
                    = (_Float16)(aS0[nt][reg] + aA0[nt][reg]);
                *(_Float16*)(BIG1 + (q * 4 + reg) * BIG_STR + (nt * 16 + c) * 2)
                    = (_Float16)(aS1[nt][reg] + aA1[nt][reg]);
            }
    }
    lds_order();

    // ========== FN + FO, both groups (4 independent streams) ===============
    {
        f16x8 An00 = lds_af(BIG0, BIG_STR, 0, lane);
        f16x8 An01 = lds_af(BIG0, BIG_STR, 64, lane);
        f16x8 Ao00 = lds_af(BG20, BIG_STR, 0, lane);
        f16x8 Ao01 = lds_af(BG20, BIG_STR, 64, lane);
        f16x8 An10 = lds_af(BIG1, BIG_STR, 0, lane);
        f16x8 An11 = lds_af(BIG1, BIG_STR, 64, lane);
        f16x8 Ao10 = lds_af(BG21, BIG_STR, 0, lane);
        f16x8 Ao11 = lds_af(BG21, BIG_STR, 64, lane);
        #pragma unroll
        for (int nt = 0; nt < 4; ++nt) {
            f16x8 Bn0 = load_bh(wsf, FR_FN + nt, lane);
            f16x8 Bn1 = load_bh(wsf, FR_FN + 4 + nt, lane);
            f16x8 Bo0 = load_bh(wsf, FR_FO + nt, lane);
            f16x8 Bo1 = load_bh(wsf, FR_FO + 4 + nt, lane);
            float bfn = BFN[nt * 16 + c], bfo = BFO[nt * 16 + c];
            f32x4 cn0 = mfma1(An01, Bn1, mfma1(An00, Bn0, cinit(bfn)));
            f32x4 co0 = mfma1(Ao01, Bo1, mfma1(Ao00, Bo0, cinit(bfo)));
            f32x4 cn1 = mfma1(An11, Bn1, mfma1(An10, Bn0, cinit(bfn)));
            f32x4 co1 = mfma1(Ao11, Bo1, mfma1(Ao10, Bo0, cinit(bfo)));
            #pragma unroll
            for (int reg = 0; reg < 4; ++reg) {
                int off = (q * 4 + reg) * BIG_STR + (nt * 16 + c) * 2;
                *(_Float16*)(BIG0 + off) = (_Float16)fmaxf(cn0[reg], 0.f);
                *(_Float16*)(BG20 + off) = (_Float16)fmaxf(co0[reg], 0.f);
                *(_Float16*)(BIG1 + off) = (_Float16)fmaxf(cn1[reg], 0.f);
                *(_Float16*)(BG21 + off) = (_Float16)fmaxf(co1[reg], 0.f);
            }
        }
    }
    lds_order();

    // ========== PSI both groups: h3 = relu(g@WG + z_n@ZN + z_o@ZO) =========
    {
        f16x8 An00 = lds_af(BIG0, BIG_STR, 0, lane);
        f16x8 An01 = lds_af(BIG0, BIG_STR, 64, lane);
        f16x8 Ao00 = lds_af(BG20, BIG_STR, 0, lane);
        f16x8 Ao01 = lds_af(BG20, BIG_STR, 64, lane);
        f16x8 An10 = lds_af(BIG1, BIG_STR, 0, lane);
        f16x8 An11 = lds_af(BIG1, BIG_STR, 64, lane);
        f16x8 Ao10 = lds_af(BG21, BIG_STR, 0, lane);
        f16x8 Ao11 = lds_af(BG21, BIG_STR, 64, lane);
        #pragma unroll
        for (int nt = 0; nt < 4; ++nt) {
            f16x8 Bg  = load_bh(wsf, FR_WG + nt, lane);
            f16x8 Bn0 = load_bh(wsf, FR_ZN + nt, lane);
            f16x8 Bn1 = load_bh(wsf, FR_ZN + 4 + nt, lane);
            f16x8 Bo0 = load_bh(wsf, FR_ZO + nt, lane);
            f16x8 Bo1 = load_bh(wsf, FR_ZO + 4 + nt, lane);
            f32x4 c0 = mfma1(gA0.v, Bg, ZC);
            c0 = mfma1(An00, Bn0, c0);
            c0 = mfma1(An01, Bn1, c0);
            c0 = mfma1(Ao00, Bo0, c0);
            c0 = mfma1(Ao01, Bo1, c0);
            f32x4 c1 = mfma1(gA1.v, Bg, ZC);
            c1 = mfma1(An10, Bn0, c1);
            c1 = mfma1(An11, Bn1, c1);
            c1 = mfma1(Ao10, Bo0, c1);
            c1 = mfma1(Ao11, Bo1, c1);
            #pragma unroll
            for (int reg = 0; reg < 4; ++reg) {
                int off = (q * 4 + reg) * BIG_STR + (nt * 16 + c) * 2;
                *(_Float16*)(BIG0 + off) = (_Float16)fmaxf(c0[reg], 0.f);
                *(_Float16*)(BIG1 + off) = (_Float16)fmaxf(c1[reg], 0.f);
            }
        }
    }
    lds_order();

    // ========== PSI2 both groups -> OUT ====================================
    {
        float b_p2 = (c < 2) ? bpsi2[c] : 0.f;
        f16x8 Bp20 = load_bh(wsf, FR_PSI2 + 0, lane);
        f16x8 Bp21 = load_bh(wsf, FR_PSI2 + 1, lane);
        f16x8 A00 = lds_af(BIG0, BIG_STR, 0, lane);
        f16x8 A01 = lds_af(BIG0, BIG_STR, 64, lane);
        f16x8 A10 = lds_af(BIG1, BIG_STR, 0, lane);
        f16x8 A11 = lds_af(BIG1, BIG_STR, 64, lane);
        f32x4 c0 = mfma1(A01, Bp21, mfma1(A00, Bp20, cinit(b_p2)));
        f32x4 c1 = mfma1(A11, Bp21, mfma1(A10, Bp20, cinit(b_p2)));
        if (c < 2) {
            #pragma unroll
            for (int reg = 0; reg < 4; ++reg) {
                *(float*)(OUT0 + (q * 4 + reg) * 8 + c * 4) = c0[reg];
                *(float*)(OUT1 + (q * 4 + reg) * 8 + c * 4) = c1[reg];
            }
        }
    }
    lds_order();

    // epilogue, both groups
    if (lane < 16) {
        float2 a0 = *(const float2*)(OUT0 + lane * 8);
        float2 b0 = *(const float2*)(BAR0 + lane * 8);
        float u0 = two_tanh(a0.x) + b0.x;
        float v0 = two_tanh(a0.y) + b0.y;
        float ia0 = fmaxf(fmaxf(fabsf(u0), fabsf(v0)) * 0.5f, 1.0f);
        float r0 = fast_rcp(ia0);
        float2 o0; o0.x = u0 * r0; o0.y = v0 * r0;
        *(float2*)(out + (size_t)(row0 + lane) * 2) = o0;

        float2 a1 = *(const float2*)(OUT1 + lane * 8);
        float2 b1 = *(const float2*)(BAR1 + lane * 8);
        float u1 = two_tanh(a1.x) + b1.x;
        float v1 = two_tanh(a1.y) + b1.y;
        float ia1 = fmaxf(fmaxf(fabsf(u1), fabsf(v1)) * 0.5f, 1.0f);
        float r1 = fast_rcp(ia1);
        float2 o1; o1.x = u1 * r1; o1.y = v1 * r1;
        *(float2*)(out + (size_t)(row1 + lane) * 2) = o1;
    }
}

extern "C" void kernel_launch(void* const* d_in, const int* in_sizes, int n_in,
                              void* d_out, int out_size, void* d_ws, size_t ws_size,
                              hipStream_t stream) {
    const float* x     = (const float*)d_in[0];
    const float* Wp1n  = (const float*)d_in[1];
    const float* bp1n  = (const float*)d_in[2];
    const float* Wp2n  = (const float*)d_in[3];
    const float* bp2n  = (const float*)d_in[4];
    const float* Wr1n  = (const float*)d_in[5];
    const float* br1n  = (const float*)d_in[6];
    const float* Wr2n  = (const float*)d_in[7];
    const float* br2n  = (const float*)d_in[8];
    const float* Wp1o  = (const float*)d_in[9];
    const float* bp1o  = (const float*)d_in[10];
    const float* Wp2o  = (const float*)d_in[11];
    const float* bp2o  = (const float*)d_in[12];
    const float* Wr1o  = (const float*)d_in[13];
    const float* br1o  = (const float*)d_in[14];
    const float* Wr2o  = (const float*)d_in[15];
    const float* br2o  = (const float*)d_in[16];
    const float* Wpsi1 = (const float*)d_in[17];
    const float* bpsi1 = (const float*)d_in[18];
    const float* Wpsi2 = (const float*)d_in[19];
    const float* bpsi2 = (const float*)d_in[20];
    float* out = (float*)d_out;

    int nb = in_sizes[0] / XW;               // 131072
    _Float16* wsf = (_Float16*)d_ws;         // ~56 KB frag+bias table

    bn_prep<<<N_FRAGS + 4, 64, 0, stream>>>(Wp1n, Wp2n, Wr1n, Wr2n,
                                            Wp1o, Wp2o, Wr1o, Wr2o,
                                            Wpsi1, Wpsi2,
                                            bp1n, bp1o, bp2n, bp2o,
                                            br1n, br1o, br2n, br2o,
                                            bpsi1, wsf);

    int groups = (nb + 15) / 16;             // 8192
    int blocks = (groups + 7) / 8;           // 1024 (8 groups per block)
    bn_main<<<blocks, 256, 0, stream>>>(x, wsf, bpsi2, out, nb);
}

// Round 9
// 135.907 us; speedup vs baseline: 1.1094x; 1.1094x over previous
//
#include <hip/hip_runtime.h>
#include <math.h>

// ---------------------------------------------------------------------------
// Barrier_Net, full-f16 MFMA (16x16x32), TWO-GROUPS-PER-WAVE pipeline (R20).
// R19 retest with REGISTER DISCIPLINE. R19's counters showed the 2-group
// version spilled (VGPR_Count=64 vs ~130 live; WRITE_SIZE 28.7MB vs 1MB
// output -> scratch traffic; all utils collapsed) so the ILP hypothesis was
// never actually tested. R20 fixes the register budget:
//   * __launch_bounds__(256,3): VGPR cap ~170 (R19's effective cap was 64).
//   * MERGED accumulator: accT is seeded by the packed-sum MFMA (SPN/SPO
//     frags, bias via f32 C-init) and the per-term |x| loop adds into the
//     SAME registers -> 16 acc VGPRs/group in S1N instead of 32. Peak live
//     ~95 VGPRs, no spill.
//   * Everything else = R19: 2 independent 16-row groups per wave, stage
//     bodies duplicated {g0,g1} for static-scheduler ILP; B-frags shared;
//     S1O (register-only) runs while NBA staging stores land.
// Sum relu(x) = (Sum x + Sum |x|)/2 identity (R16); /2 folded into FN/FO.
// Algebraic fusion (R17): FN/FO=0.5*Wp2@Wr1 (+bias_f), ZN/ZO=Wr2@Wpsi1,
// WG = Wpsi1[32:36] + combined bias row @k4.
// A-frag: A[m=lane&15][k=(lane>>4)*8+j]; B-frag: B[k=(lane>>4)*8+j][n=lane&15]
// C/D: col=lane&15, row=(lane>>4)*4+reg.  (HW-verified R7..R12)
// No __syncthreads; wave-private LDS + lds_order() fences (R11-proven).
// LDS: 8 groups x 4864 B = 38912 B/block. nb=131072 -> 1024 blocks exact.
// ---------------------------------------------------------------------------

typedef __attribute__((ext_vector_type(8))) _Float16 f16x8;
typedef __attribute__((ext_vector_type(2))) __fp16 fp16x2;
typedef __attribute__((ext_vector_type(4))) float f32x4;

#define XW 85     // floats per input row

// ---- B-frag table in d_ws ----
#define FR_S1N  0    // 4: Wp1n K=4, bias bp1n @k4
#define FR_S1O  4    // 4: Wp1o K=2, bias bp1o @k2
#define FR_FN   8    // 8: 0.5*Wp2n@Wr1n  (kk*4+nt)
#define FR_FO   16   // 8: 0.5*Wp2o@Wr1o
#define FR_ZN   24   // 8: Wr2n@Wpsi1[0:16]
#define FR_ZO   32   // 8: Wr2o@Wpsi1[16:32]
#define FR_WG   40   // 4: Wpsi1[32:36] K=4, combined PSI1 bias @k4
#define FR_PSI2 44   // 2: Wpsi2 K=64 N=2
#define FR_SPN  46   // 4: packed-sum B for S1N: B[k][n]=Wp1n[k&3][n]
#define FR_SPO  50   // 4: packed-sum B for S1O: k<16 ? Wp1o[k&1][n] : 0
#define N_FRAGS 54
// f32 bias area at 54*512 f16: [0..63]=bias_fn, [64..127]=bias_fo,
//                              [128..191]=16*bp1n, [192..255]=8*bp1o

// ---- per-GROUP LDS layout (bytes); 8 groups (2/wave x 4 waves) per block ----
#define BIG_STR 144
#define L_BIG  0        // 2304  NBA staging / h1n / z_n / h3
#define L_BIG2 2304     // 2304  h1o / z_o
#define L_OUT  4608     // 128
#define L_BAR  4736     // 128
#define GRP_LDS 4864    // x8 groups = 38912 B/block
#define NBA_STR 136     // staging tile stride inside BIG region

#define H16_ONE 0x00003C00u   // f16 1.0 in low half of a dword

__device__ __forceinline__ float fast_rcp(float x)  { return __builtin_amdgcn_rcpf(x); }
__device__ __forceinline__ float fast_sqrt(float x) { return __builtin_amdgcn_sqrtf(x); }

__device__ __forceinline__ float two_tanh(float a) {
    float ax = fabsf(a);
    float e = __expf(2.0f * ax);
    float t = 1.0f - 2.0f * fast_rcp(e + 1.0f);
    return copysignf(2.0f * t, a);
}

// Compiler-only ordering barrier for wave-private LDS (R11-proven safe).
__device__ __forceinline__ void lds_order() {
    __asm__ __volatile__("" ::: "memory");
}

__device__ __forceinline__ unsigned pk2(float a, float b) {
    union { fp16x2 h; unsigned u; } t;
    t.h = __builtin_amdgcn_cvt_pkrtz(a, b);
    return t.u;
}
__device__ __forceinline__ f16x8 lds_af(const char* area, int stride, int off, int lane) {
    int mm = lane & 15, qq = lane >> 4;
    return *(const f16x8*)(area + mm * stride + off + qq * 16);
}
__device__ __forceinline__ f16x8 load_bh(const _Float16* wsf, int frag, int lane) {
    return ((const f16x8*)(wsf + (size_t)frag * 512))[lane];
}
__device__ __forceinline__ f32x4 cinit(float b) {
    f32x4 c; c[0] = b; c[1] = b; c[2] = b; c[3] = b; return c;
}
__device__ __forceinline__ f32x4 mfma1(f16x8 a, f16x8 b, f32x4 c) {
    return __builtin_amdgcn_mfma_f32_16x16x32_f16(a, b, c, 0, 0, 0);
}

// ---------------------------------------------------------------------------
// prep: pack (pre-composed) weights into f16 B-frag blocks + f32 bias rows.
// (unchanged from R18/R19)
// ---------------------------------------------------------------------------
__global__ void bn_prep(const float* __restrict__ Wp1n, const float* __restrict__ Wp2n,
                        const float* __restrict__ Wr1n, const float* __restrict__ Wr2n,
                        const float* __restrict__ Wp1o, const float* __restrict__ Wp2o,
                        const float* __restrict__ Wr1o, const float* __restrict__ Wr2o,
                        const float* __restrict__ Wpsi1, const float* __restrict__ Wpsi2,
                        const float* __restrict__ bp1n, const float* __restrict__ bp1o,
                        const float* __restrict__ bp2n, const float* __restrict__ bp2o,
                        const float* __restrict__ br1n, const float* __restrict__ br1o,
                        const float* __restrict__ br2n, const float* __restrict__ br2o,
                        const float* __restrict__ bpsi1,
                        _Float16* __restrict__ wsf)
{
    int f = blockIdx.x;
    int lane = threadIdx.x;   // 64
    int q = lane >> 4, c = lane & 15;

    if (f >= N_FRAGS) {
        float* dst = (float*)(wsf + (size_t)N_FRAGS * 512) + (f - N_FRAGS) * 64;
        if (lane < 64) {
            if (f == N_FRAGS) {
                float s = 0.f;
                for (int e = 0; e < 16; ++e) s = fmaf(bp2n[e], Wr1n[e * 64 + lane], s);
                dst[lane] = 16.f * s + br1n[lane];
            } else if (f == N_FRAGS + 1) {
                float s = 0.f;
                for (int e = 0; e < 16; ++e) s = fmaf(bp2o[e], Wr1o[e * 64 + lane], s);
                dst[lane] = 8.f * s + br1o[lane];
            } else if (f == N_FRAGS + 2) {
                dst[lane] = 16.f * bp1n[lane];
            } else {
                dst[lane] = 8.f * bp1o[lane];
            }
        }
        return;
    }

    _Float16* dstf = wsf + (size_t)f * 512 + lane * 8;

    if (f < 8) {
        const float* W   = (f < 4) ? Wp1n : Wp1o;
        const float* bia = (f < 4) ? bp1n : bp1o;
        int K  = (f < 4) ? 4 : 2;
        int nt = f & 3;
        for (int j = 0; j < 8; ++j) {
            int k = q * 8 + j;
            int n = nt * 16 + c;
            float v = 0.f;
            if (k < K) v = W[k * 64 + n];
            else if (k == K) v = bia[n];
            dstf[j] = (_Float16)v;
        }
    } else if (f < 24) {
        int rel = (f - 8) & 7;
        bool isN = f < 16;
        const float* Wa = isN ? Wp2n : Wp2o;
        const float* Wb = isN ? Wr1n : Wr1o;
        int kk = rel >> 2, nt = rel & 3;
        for (int j = 0; j < 8; ++j) {
            int k = kk * 32 + q * 8 + j;
            int n = nt * 16 + c;
            float s = 0.f;
            for (int e = 0; e < 16; ++e) s = fmaf(Wa[k * 16 + e], Wb[e * 64 + n], s);
            dstf[j] = (_Float16)(0.5f * s);
        }
    } else if (f < 40) {
        int rel = (f - 24) & 7;
        bool isN = f < 32;
        const float* Wa = isN ? Wr2n : Wr2o;
        int roff = isN ? 0 : 16;
        int kk = rel >> 2, nt = rel & 3;
        for (int j = 0; j < 8; ++j) {
            int k = kk * 32 + q * 8 + j;
            int n = nt * 16 + c;
            float s = 0.f;
            for (int e = 0; e < 16; ++e) s = fmaf(Wa[k * 16 + e], Wpsi1[(roff + e) * 64 + n], s);
            dstf[j] = (_Float16)s;
        }
    } else if (f < 44) {
        int nt = f - 40;
        for (int j = 0; j < 8; ++j) {
            int k = q * 8 + j;
            int n = nt * 16 + c;
            float v = 0.f;
            if (k < 4) v = Wpsi1[(32 + k) * 64 + n];
            else if (k == 4) {
                float s = bpsi1[n];
                for (int e = 0; e < 16; ++e) {
                    s = fmaf(br2n[e], Wpsi1[e * 64 + n], s);
                    s = fmaf(br2o[e], Wpsi1[(16 + e) * 64 + n], s);
                }
                v = s;
            }
            dstf[j] = (_Float16)v;
        }
    } else if (f < 46) {
        int kk = f - 44;
        for (int j = 0; j < 8; ++j) {
            int k = kk * 32 + q * 8 + j;
            float v = (c < 2) ? Wpsi2[k * 2 + c] : 0.f;
            dstf[j] = (_Float16)v;
        }
    } else if (f < 50) {
        int nt = f - 46;
        for (int j = 0; j < 8; ++j) {
            int k = q * 8 + j;
            int n = nt * 16 + c;
            dstf[j] = (_Float16)Wp1n[(k & 3) * 64 + n];
        }
    } else {
        int nt = f - 50;
        for (int j = 0; j < 8; ++j) {
            int k = q * 8 + j;
            int n = nt * 16 + c;
            float v = (k < 16) ? Wp1o[(k & 1) * 64 + n] : 0.f;
            dstf[j] = (_Float16)v;
        }
    }
}

// ---------------------------------------------------------------------------
// main: 2 groups per wave; block 256 = 4 waves = 8 groups.
// ---------------------------------------------------------------------------
__global__ __launch_bounds__(256, 3) void bn_main(
    const float* __restrict__ x, const _Float16* __restrict__ wsf,
    const float* __restrict__ bpsi2,
    float* __restrict__ out, int nb)
{
    __shared__ char smem[8 * GRP_LDS];
    const int lane = threadIdx.x & 63;
    const int wid  = threadIdx.x >> 6;            // 0..3
    const int g0   = blockIdx.x * 8 + wid * 2;    // first group of this wave
    const int row0 = g0 * 16;
    const int row1 = row0 + 16;

    char* Gl0  = smem + (wid * 2) * GRP_LDS;
    char* Gl1  = Gl0 + GRP_LDS;
    char* BIG0 = Gl0 + L_BIG;   char* BIG1 = Gl1 + L_BIG;
    char* BG20 = Gl0 + L_BIG2;  char* BG21 = Gl1 + L_BIG2;
    char* OUT0 = Gl0 + L_OUT;   char* OUT1 = Gl1 + L_OUT;
    char* BAR0 = Gl0 + L_BAR;   char* BAR1 = Gl1 + L_BAR;
    char* NBA0 = BIG0;          char* NBA1 = BIG1;   // staging aliases BIG

    const int m = lane & 15, q = lane >> 4, c = m;
    const float* xg0   = x + (size_t)row0 * XW;
    const float* xg1   = x + (size_t)row1 * XW;
    const float* xrow0 = xg0 + (size_t)m * XW;
    const float* xrow1 = xg1 + (size_t)m * XW;

    const float* BFN = (const float*)(wsf + (size_t)N_FRAGS * 512);  // bias_fn
    const float* BFO = BFN + 64;                                     // bias_fo
    const float* BSN = BFN + 128;                                    // 16*bp1n
    const float* BSO = BFN + 192;                                    // 8*bp1o

    const f32x4 ZC = cinit(0.f);

    // ---- stage neighbor features -> NBA0/NBA1 (interleaved loads) ----
    {
        int ln5 = lane >> 5;                 // 0/1
        int pr  = lane & 31;
        int mm0 = pr >> 1, fp = pr & 1;
        int dbo = mm0 * NBA_STR + fp * 4;
        const float* s00 = xg0 + (size_t)ln5 * XW + 5 + pr * 2;
        const float* s10 = xg1 + (size_t)ln5 * XW + 5 + pr * 2;
        #pragma unroll
        for (int t = 0; t < 8; ++t) {
            const float* sa = s00 + (size_t)(2 * t) * XW;
            const float* sb = s10 + (size_t)(2 * t) * XW;
            *(unsigned*)(NBA0 + dbo + (2 * t + ln5) * 8) = pk2(sa[0], sa[1]);
            *(unsigned*)(NBA1 + dbo + (2 * t + ln5) * 8) = pk2(sb[0], sb[1]);
        }
    }

    // ---- gA (PSI A-operand) built early (8 VGPR total, cheap) ----
    union { f16x8 v; unsigned u[4]; } gA0, gA1;
    gA0.u[0] = pk2(xrow0[1], xrow0[2]);
    gA0.u[1] = pk2(xrow0[3], xrow0[4]);
    gA0.u[2] = H16_ONE; gA0.u[3] = 0;
    gA1.u[0] = pk2(xrow1[1], xrow1[2]);
    gA1.u[1] = pk2(xrow1[3], xrow1[4]);
    gA1.u[2] = H16_ONE; gA1.u[3] = 0;

    // ---- obstacle features -> registers (die after S1O) ----
    unsigned obs0[8], obs1[8];
    #pragma unroll
    for (int t = 0; t < 8; ++t) {
        obs0[t] = pk2(xrow0[69 + 2 * t], xrow0[70 + 2 * t]);
        obs1[t] = pk2(xrow1[69 + 2 * t], xrow1[70 + 2 * t]);
    }

    // ---- barrier terms for both rows ----
    {
        float bx0 = 0.f, by0 = 0.f, bx1 = 0.f, by1 = 0.f;
        #pragma unroll
        for (int i = 0; i < 4; ++i) {
            int n = 4 * q + i;
            float p0x = -xrow0[5 + 4 * n], p0y = -xrow0[6 + 4 * n];
            float n0 = fast_sqrt(p0x * p0x + p0y * p0y);
            float c0 = 0.05f * fast_rcp(n0 * (n0 - 0.3f));
            bx0 = fmaf(c0, p0x, bx0); by0 = fmaf(c0, p0y, by0);
            float p1x = -xrow1[5 + 4 * n], p1y = -xrow1[6 + 4 * n];
            float n1 = fast_sqrt(p1x * p1x + p1y * p1y);
            float c1 = 0.05f * fast_rcp(n1 * (n1 - 0.3f));
            bx1 = fmaf(c1, p1x, bx1); by1 = fmaf(c1, p1y, by1);
        }
        #pragma unroll
        for (int i = 0; i < 2; ++i) {
            int o = 2 * q + i;
            float p0x = -xrow0[69 + 2 * o], p0y = -xrow0[70 + 2 * o];
            float n0 = fast_sqrt(p0x * p0x + p0y * p0y);
            float c0 = 0.05f * fast_rcp(n0 * (n0 - 0.3f));
            bx0 = fmaf(c0, p0x, bx0); by0 = fmaf(c0, p0y, by0);
            float p1x = -xrow1[69 + 2 * o], p1y = -xrow1[70 + 2 * o];
            float n1 = fast_sqrt(p1x * p1x + p1y * p1y);
            float c1 = 0.05f * fast_rcp(n1 * (n1 - 0.3f));
            bx1 = fmaf(c1, p1x, bx1); by1 = fmaf(c1, p1y, by1);
        }
        bx0 += __shfl_xor(bx0, 16); by0 += __shfl_xor(by0, 16);
        bx0 += __shfl_xor(bx0, 32); by0 += __shfl_xor(by0, 32);
        bx1 += __shfl_xor(bx1, 16); by1 += __shfl_xor(by1, 16);
        bx1 += __shfl_xor(bx1, 32); by1 += __shfl_xor(by1, 32);
        if (q == 0) {
            float2 b0; b0.x = bx0; b0.y = by0; *(float2*)(BAR0 + m * 8) = b0;
            float2 b1; b1.x = bx1; b1.y = by1; *(float2*)(BAR1 + m * 8) = b1;
        }
    }

    // ========== S1O both groups (register-only; NBA stores still landing) ==
    // accT = packed-sum (1 MFMA, bias in C-init) then += |x| per term.
    {
        f16x8 Bspo[4], Bs1o[4];
        #pragma unroll
        for (int nt = 0; nt < 4; ++nt) {
            Bspo[nt] = load_bh(wsf, FR_SPO + nt, lane);
            Bs1o[nt] = load_bh(wsf, FR_S1O + nt, lane);
        }
        union { f16x8 v; unsigned u[4]; } Ap0, Ap1;
        #pragma unroll
        for (int j = 0; j < 4; ++j) {
            Ap0.u[j] = q == 0 ? obs0[j] : (q == 1 ? obs0[4 + j] : 0u);
            Ap1.u[j] = q == 0 ? obs1[j] : (q == 1 ? obs1[4 + j] : 0u);
        }
        f32x4 aT0[4], aT1[4];
        #pragma unroll
        for (int nt = 0; nt < 4; ++nt) {
            float b = BSO[nt * 16 + c];
            aT0[nt] = mfma1(Ap0.v, Bspo[nt], cinit(b));
            aT1[nt] = mfma1(Ap1.v, Bspo[nt], cinit(b));
        }
        union { f16x8 v; unsigned u[4]; } A0, A1;
        A0.u[1] = H16_ONE; A0.u[2] = 0; A0.u[3] = 0;
        A1.u[1] = H16_ONE; A1.u[2] = 0; A1.u[3] = 0;
        #pragma unroll
        for (int oo = 0; oo < 8; ++oo) {
            A0.u[0] = obs0[oo];
            A1.u[0] = obs1[oo];
            #pragma unroll
            for (int nt = 0; nt < 4; ++nt) {
                f32x4 c0 = mfma1(A0.v, Bs1o[nt], ZC);
                f32x4 c1 = mfma1(A1.v, Bs1o[nt], ZC);
                #pragma unroll
                for (int reg = 0; reg < 4; ++reg) {
                    aT0[nt][reg] += fabsf(c0[reg]);
                    aT1[nt][reg] += fabsf(c1[reg]);
                }
            }
        }
        #pragma unroll
        for (int nt = 0; nt < 4; ++nt)
            #pragma unroll
            for (int reg = 0; reg < 4; ++reg) {
                *(_Float16*)(BG20 + (q * 4 + reg) * BIG_STR + (nt * 16 + c) * 2)
                    = (_Float16)aT0[nt][reg];
                *(_Float16*)(BG21 + (q * 4 + reg) * BIG_STR + (nt * 16 + c) * 2)
                    = (_Float16)aT1[nt][reg];
            }
    }
    lds_order();   // NBA staging stores ordered before S1N reads

    // ========== S1N both groups (merged accT; shared B frags) ==============
    {
        f16x8 Bspn[4], Bs1n[4];
        #pragma unroll
        for (int nt = 0; nt < 4; ++nt) {
            Bspn[nt] = load_bh(wsf, FR_SPN + nt, lane);
            Bs1n[nt] = load_bh(wsf, FR_S1N + nt, lane);
        }
        const int m8 = m * 8;
        // packed A: k=q*8+j -> nbr (k>>2): Ap0 = nbrs {2q,2q+1}, Ap1 = +8
        union { f16x8 v; uint2 h[2]; } P00, P01;
        P00.h[0] = *(const uint2*)(NBA0 + (2 * q) * NBA_STR + m8);
        P00.h[1] = *(const uint2*)(NBA0 + (2 * q + 1) * NBA_STR + m8);
        P01.h[0] = *(const uint2*)(NBA0 + (2 * q + 8) * NBA_STR + m8);
        P01.h[1] = *(const uint2*)(NBA0 + (2 * q + 9) * NBA_STR + m8);
        union { f16x8 v; uint2 h[2]; } P10, P11;
        P10.h[0] = *(const uint2*)(NBA1 + (2 * q) * NBA_STR + m8);
        P10.h[1] = *(const uint2*)(NBA1 + (2 * q + 1) * NBA_STR + m8);
        P11.h[0] = *(const uint2*)(NBA1 + (2 * q + 8) * NBA_STR + m8);
        P11.h[1] = *(const uint2*)(NBA1 + (2 * q + 9) * NBA_STR + m8);

        f32x4 aT0[4], aT1[4];
        #pragma unroll
        for (int nt = 0; nt < 4; ++nt) {
            float b = BSN[nt * 16 + c];
            aT0[nt] = mfma1(P01.v, Bspn[nt], mfma1(P00.v, Bspn[nt], cinit(b)));
            aT1[nt] = mfma1(P11.v, Bspn[nt], mfma1(P10.v, Bspn[nt], cinit(b)));
        }
        union { f16x8 v; unsigned u[4]; uint2 h[2]; } A0, A1;
        A0.u[2] = H16_ONE; A0.u[3] = 0;
        A1.u[2] = H16_ONE; A1.u[3] = 0;
        #pragma unroll
        for (int mm = 0; mm < 16; ++mm) {
            A0.h[0] = *(const uint2*)(NBA0 + mm * NBA_STR + m8);
            A1.h[0] = *(const uint2*)(NBA1 + mm * NBA_STR + m8);
            #pragma unroll
            for (int nt = 0; nt < 4; ++nt) {
                f32x4 c0 = mfma1(A0.v, Bs1n[nt], ZC);
                f32x4 c1 = mfma1(A1.v, Bs1n[nt], ZC);
                #pragma unroll
                for (int reg = 0; reg < 4; ++reg) {
                    aT0[nt][reg] += fabsf(c0[reg]);
                    aT1[nt][reg] += fabsf(c1[reg]);
                }
            }
        }
        lds_order();   // NBA reads done; BIG stores below alias it
        #pragma unroll
        for (int nt = 0; nt < 4; ++nt)
            #pragma unroll
            for (int reg = 0; reg < 4; ++reg) {
                *(_Float16*)(BIG0 + (q * 4 + reg) * BIG_STR + (nt * 16 + c) * 2)
                    = (_Float16)aT0[nt][reg];
                *(_Float16*)(BIG1 + (q * 4 + reg) * BIG_STR + (nt * 16 + c) * 2)
                    = (_Float16)aT1[nt][reg];
            }
    }
    lds_order();

    // ========== FN + FO, both groups (4 independent streams) ===============
    {
        f16x8 An00 = lds_af(BIG0, BIG_STR, 0, lane);
        f16x8 An01 = lds_af(BIG0, BIG_STR, 64, lane);
        f16x8 Ao00 = lds_af(BG20, BIG_STR, 0, lane);
        f16x8 Ao01 = lds_af(BG20, BIG_STR, 64, lane);
        f16x8 An10 = lds_af(BIG1, BIG_STR, 0, lane);
        f16x8 An11 = lds_af(BIG1, BIG_STR, 64, lane);
        f16x8 Ao10 = lds_af(BG21, BIG_STR, 0, lane);
        f16x8 Ao11 = lds_af(BG21, BIG_STR, 64, lane);
        #pragma unroll
        for (int nt = 0; nt < 4; ++nt) {
            f16x8 Bn0 = load_bh(wsf, FR_FN + nt, lane);
            f16x8 Bn1 = load_bh(wsf, FR_FN + 4 + nt, lane);
            f16x8 Bo0 = load_bh(wsf, FR_FO + nt, lane);
            f16x8 Bo1 = load_bh(wsf, FR_FO + 4 + nt, lane);
            float bfn = BFN[nt * 16 + c], bfo = BFO[nt * 16 + c];
            f32x4 cn0 = mfma1(An01, Bn1, mfma1(An00, Bn0, cinit(bfn)));
            f32x4 co0 = mfma1(Ao01, Bo1, mfma1(Ao00, Bo0, cinit(bfo)));
            f32x4 cn1 = mfma1(An11, Bn1, mfma1(An10, Bn0, cinit(bfn)));
            f32x4 co1 = mfma1(Ao11, Bo1, mfma1(Ao10, Bo0, cinit(bfo)));
            #pragma unroll
            for (int reg = 0; reg < 4; ++reg) {
                int off = (q * 4 + reg) * BIG_STR + (nt * 16 + c) * 2;
                *(_Float16*)(BIG0 + off) = (_Float16)fmaxf(cn0[reg], 0.f);
                *(_Float16*)(BG20 + off) = (_Float16)fmaxf(co0[reg], 0.f);
                *(_Float16*)(BIG1 + off) = (_Float16)fmaxf(cn1[reg], 0.f);
                *(_Float16*)(BG21 + off) = (_Float16)fmaxf(co1[reg], 0.f);
            }
        }
    }
    lds_order();

    // ========== PSI both groups: h3 = relu(g@WG + z_n@ZN + z_o@ZO) =========
    {
        f16x8 An00 = lds_af(BIG0, BIG_STR, 0, lane);
        f16x8 An01 = lds_af(BIG0, BIG_STR, 64, lane);
        f16x8 Ao00 = lds_af(BG20, BIG_STR, 0, lane);
        f16x8 Ao01 = lds_af(BG20, BIG_STR, 64, lane);
        f16x8 An10 = lds_af(BIG1, BIG_STR, 0, lane);
        f16x8 An11 = lds_af(BIG1, BIG_STR, 64, lane);
        f16x8 Ao10 = lds_af(BG21, BIG_STR, 0, lane);
        f16x8 Ao11 = lds_af(BG21, BIG_STR, 64, lane);
        #pragma unroll
        for (int nt = 0; nt < 4; ++nt) {
            f16x8 Bg  = load_bh(wsf, FR_WG + nt, lane);
            f16x8 Bn0 = load_bh(wsf, FR_ZN + nt, lane);
            f16x8 Bn1 = load_bh(wsf, FR_ZN + 4 + nt, lane);
            f16x8 Bo0 = load_bh(wsf, FR_ZO + nt, lane);
            f16x8 Bo1 = load_bh(wsf, FR_ZO + 4 + nt, lane);
            f32x4 c0 = mfma1(gA0.v, Bg, ZC);
            c0 = mfma1(An00, Bn0, c0);
            c0 = mfma1(An01, Bn1, c0);
            c0 = mfma1(Ao00, Bo0, c0);
            c0 = mfma1(Ao01, Bo1, c0);
            f32x4 c1 = mfma1(gA1.v, Bg, ZC);
            c1 = mfma1(An10, Bn0, c1);
            c1 = mfma1(An11, Bn1, c1);
            c1 = mfma1(Ao10, Bo0, c1);
            c1 = mfma1(Ao11, Bo1, c1);
            #pragma unroll
            for (int reg = 0; reg < 4; ++reg) {
                int off = (q * 4 + reg) * BIG_STR + (nt * 16 + c) * 2;
                *(_Float16*)(BIG0 + off) = (_Float16)fmaxf(c0[reg], 0.f);
                *(_Float16*)(BIG1 + off) = (_Float16)fmaxf(c1[reg], 0.f);
            }
        }
    }
    lds_order();

    // ========== PSI2 both groups -> OUT ====================================
    {
        float b_p2 = (c < 2) ? bpsi2[c] : 0.f;
        f16x8 Bp20 = load_bh(wsf, FR_PSI2 + 0, lane);
        f16x8 Bp21 = load_bh(wsf, FR_PSI2 + 1, lane);
        f16x8 A00 = lds_af(BIG0, BIG_STR, 0, lane);
        f16x8 A01 = lds_af(BIG0, BIG_STR, 64, lane);
        f16x8 A10 = lds_af(BIG1, BIG_STR, 0, lane);
        f16x8 A11 = lds_af(BIG1, BIG_STR, 64, lane);
        f32x4 c0 = mfma1(A01, Bp21, mfma1(A00, Bp20, cinit(b_p2)));
        f32x4 c1 = mfma1(A11, Bp21, mfma1(A10, Bp20, cinit(b_p2)));
        if (c < 2) {
            #pragma unroll
            for (int reg = 0; reg < 4; ++reg) {
                *(float*)(OUT0 + (q * 4 + reg) * 8 + c * 4) = c0[reg];
                *(float*)(OUT1 + (q * 4 + reg) * 8 + c * 4) = c1[reg];
            }
        }
    }
    lds_order();

    // epilogue, both groups
    if (lane < 16) {
        float2 a0 = *(const float2*)(OUT0 + lane * 8);
        float2 b0 = *(const float2*)(BAR0 + lane * 8);
        float u0 = two_tanh(a0.x) + b0.x;
        float v0 = two_tanh(a0.y) + b0.y;
        float ia0 = fmaxf(fmaxf(fabsf(u0), fabsf(v0)) * 0.5f, 1.0f);
        float r0 = fast_rcp(ia0);
        float2 o0; o0.x = u0 * r0; o0.y = v0 * r0;
        *(float2*)(out + (size_t)(row0 + lane) * 2) = o0;

        float2 a1 = *(const float2*)(OUT1 + lane * 8);
        float2 b1 = *(const float2*)(BAR1 + lane * 8);
        float u1 = two_tanh(a1.x) + b1.x;
        float v1 = two_tanh(a1.y) + b1.y;
        float ia1 = fmaxf(fmaxf(fabsf(u1), fabsf(v1)) * 0.5f, 1.0f);
        float r1 = fast_rcp(ia1);
        float2 o1; o1.x = u1 * r1; o1.y = v1 * r1;
        *(float2*)(out + (size_t)(row1 + lane) * 2) = o1;
    }
}

extern "C" void kernel_launch(void* const* d_in, const int* in_sizes, int n_in,
                              void* d_out, int out_size, void* d_ws, size_t ws_size,
                              hipStream_t stream) {
    const float* x     = (const float*)d_in[0];
    const float* Wp1n  = (const float*)d_in[1];
    const float* bp1n  = (const float*)d_in[2];
    const float* Wp2n  = (const float*)d_in[3];
    const float* bp2n  = (const float*)d_in[4];
    const float* Wr1n  = (const float*)d_in[5];
    const float* br1n  = (const float*)d_in[6];
    const float* Wr2n  = (const float*)d_in[7];
    const float* br2n  = (const float*)d_in[8];
    const float* Wp1o  = (const float*)d_in[9];
    const float* bp1o  = (const float*)d_in[10];
    const float* Wp2o  = (const float*)d_in[11];
    const float* bp2o  = (const float*)d_in[12];
    const float* Wr1o  = (const float*)d_in[13];
    const float* br1o  = (const float*)d_in[14];
    const float* Wr2o  = (const float*)d_in[15];
    const float* br2o  = (const float*)d_in[16];
    const float* Wpsi1 = (const float*)d_in[17];
    const float* bpsi1 = (const float*)d_in[18];
    const float* Wpsi2 = (const float*)d_in[19];
    const float* bpsi2 = (const float*)d_in[20];
    float* out = (float*)d_out;

    int nb = in_sizes[0] / XW;               // 131072
    _Float16* wsf = (_Float16*)d_ws;         // ~56 KB frag+bias table

    bn_prep<<<N_FRAGS + 4, 64, 0, stream>>>(Wp1n, Wp2n, Wr1n, Wr2n,
                                            Wp1o, Wp2o, Wr1o, Wr2o,
                                            Wpsi1, Wpsi2,
                                            bp1n, bp1o, bp2n, bp2o,
                                            br1n, br1o, br2n, br2o,
                                            bpsi1, wsf);

    int groups = (nb + 15) / 16;             // 8192
    int blocks = (groups + 7) / 8;           // 1024 (8 groups per block)
    bn_main<<<blocks, 256, 0, stream>>>(x, wsf, bpsi2, out, nb);
}